// Round 3
// baseline (1815.325 us; speedup 1.0000x reference)
//
#include <hip/hip_runtime.h>

// Bilinear scatter-add via 4x4-cell tile binning + LDS-privatized gather.
// Shapes fixed by the problem: N=500000, D=112, H=64, W=176.
// R2 post-mortem: per-cell binning cost 3 passes and 896MB feat re-read;
// fill had 11x write amplification (two 4B scattered stores/entry).
// R3: bin point-ids only (4B/entry) into 704 coarse tiles, fixed-capacity
// buckets (no count/scan), gather recomputes weights and accumulates a
// 16-cell x 112-ch tile in LDS; zero global atomics in the gather.

#define D     112
#define H     64
#define W     176
#define TX    4
#define TY    4
#define TXN   (W / TX)      // 44
#define TYN   (H / TY)      // 16
#define NTILE (TXN * TYN)   // 704
#define CELLS (TX * TY)     // 16
#define CAP   2048          // mean entries/tile ~1110, sigma ~33 -> safe

__global__ __launch_bounds__(256) void fill_kernel(
    const float2* __restrict__ pos,   // [N] (x, y)
    int* __restrict__ cnt,            // [NTILE], pre-zeroed
    int* __restrict__ bucket,         // [NTILE * CAP]
    int N)
{
    int p = blockIdx.x * blockDim.x + threadIdx.x;
    if (p >= N) return;

    float2 xy = pos[p];
    int x0 = (int)floorf(xy.x);
    int y0 = (int)floorf(xy.y);
    int x1 = x0 + 1, y1 = y0 + 1;

    // Inputs are in [0, W-1) x [0, H-1) so all 4 corners are in-bounds;
    // guards keep us correct if an edge value sneaks in.
    int tx0 = x0 >> 2, ty0 = y0 >> 2;
    int tx1 = (x1 < W) ? (x1 >> 2) : tx0;
    int ty1 = (y1 < H) ? (y1 >> 2) : ty0;

    bool dx = (tx1 != tx0);
    bool dy = (ty1 != ty0);

    int t00 = ty0 * TXN + tx0;
    {
        int i = atomicAdd(&cnt[t00], 1);
        if (i < CAP) bucket[t00 * CAP + i] = p;
    }
    if (dx) {
        int t = ty0 * TXN + tx1;
        int i = atomicAdd(&cnt[t], 1);
        if (i < CAP) bucket[t * CAP + i] = p;
    }
    if (dy) {
        int t = ty1 * TXN + tx0;
        int i = atomicAdd(&cnt[t], 1);
        if (i < CAP) bucket[t * CAP + i] = p;
    }
    if (dx && dy) {
        int t = ty1 * TXN + tx1;
        int i = atomicAdd(&cnt[t], 1);
        if (i < CAP) bucket[t * CAP + i] = p;
    }
}

__global__ __launch_bounds__(128) void accum_kernel(
    const float2* __restrict__ pos,
    const float* __restrict__ feat,   // [N, D]
    const int* __restrict__ cnt,
    const int* __restrict__ bucket,
    float* __restrict__ out)          // [H, W, D]
{
    const int tile = blockIdx.x;
    const int tileX0 = (tile % TXN) * TX;
    const int tileY0 = (tile / TXN) * TY;
    const int t = threadIdx.x;

    __shared__ float acc[CELLS * D];        // 7168 B
    __shared__ float sx[128], sy[128];
    __shared__ int   sp[128];

    for (int i = t; i < CELLS * D; i += 128) acc[i] = 0.0f;

    const int n = min(cnt[tile], CAP);
    const int* bk = bucket + tile * CAP;
    __syncthreads();

    for (int base = 0; base < n; base += 128) {
        int m = min(128, n - base);
        if (t < m) {
            int p = bk[base + t];
            float2 xy = pos[p];
            sp[t] = p;
            sx[t] = xy.x;
            sy[t] = xy.y;
        }
        __syncthreads();

        if (t < D) {
#pragma unroll 4
            for (int e = 0; e < m; ++e) {
                int p = sp[e];
                float f = feat[p * D + t];
                float x = sx[e], y = sy[e];
                float x0f = floorf(x), y0f = floorf(y);
                float wx = x - x0f, wy = y - y0f;
                int lx0 = (int)x0f - tileX0;
                int ly0 = (int)y0f - tileY0;
                int lx1 = lx0 + 1, ly1 = ly0 + 1;
                // corner-in-tile implies corner-in-bounds (tiles tile the grid)
                bool bx0 = (unsigned)lx0 < TX, bx1 = (unsigned)lx1 < TX;
                bool by0 = (unsigned)ly0 < TY, by1 = (unsigned)ly1 < TY;
                if (by0 & bx0) atomicAdd(&acc[(ly0 * TX + lx0) * D + t], (1.0f - wy) * (1.0f - wx) * f);
                if (by0 & bx1) atomicAdd(&acc[(ly0 * TX + lx1) * D + t], (1.0f - wy) * wx * f);
                if (by1 & bx0) atomicAdd(&acc[(ly1 * TX + lx0) * D + t], wy * (1.0f - wx) * f);
                if (by1 & bx1) atomicAdd(&acc[(ly1 * TX + lx1) * D + t], wy * wx * f);
            }
        }
        __syncthreads();
    }

    // Every cell of every tile is written -> no global memset needed.
    if (t < D) {
#pragma unroll
        for (int cell = 0; cell < CELLS; ++cell) {
            int gy = tileY0 + cell / TX;
            int gx = tileX0 + cell % TX;
            out[(gy * W + gx) * D + t] = acc[cell * D + t];
        }
    }
}

extern "C" void kernel_launch(void* const* d_in, const int* in_sizes, int n_in,
                              void* d_out, int out_size, void* d_ws, size_t ws_size,
                              hipStream_t stream) {
    const float2* pos = (const float2*)d_in[0];
    const float* feat = (const float*)d_in[1];
    float* out        = (float*)d_out;

    const int N = in_sizes[0] / 2;

    int* cnt    = (int*)d_ws;
    int* bucket = cnt + NTILE;
    // ws use: (NTILE + NTILE*CAP)*4 B ~= 5.8 MB

    hipMemsetAsync(cnt, 0, NTILE * sizeof(int), stream);

    int blocks = (N + 255) / 256;
    fill_kernel<<<blocks, 256, 0, stream>>>(pos, cnt, bucket, N);

    accum_kernel<<<NTILE, 128, 0, stream>>>(pos, feat, cnt, bucket, out);
}